// Round 12
// baseline (45.556 us; speedup 1.0000x reference)
//
#include <hip/hip_runtime.h>
#include <stdint.h>
#include <math.h>

typedef __attribute__((ext_vector_type(8))) short short8;
typedef __attribute__((ext_vector_type(16))) float f32x16;

#define DEVI static __device__ __forceinline__

constexpr int D = 256;  // feature dim
constexpr float LOG2E = 1.4426950408889634f;
constexpr float LN2   = 0.6931471805599453f;

// ws layout (bytes)
constexpr size_t WS_EIMG  = 0;                   // 16 tiles x 16384 = 262144
constexpr size_t WS_ETERM = 262144;              // 512 f32
constexpr size_t WS_WMAX  = 264192;              // 512 blk x 512 col = 1 MB
constexpr size_t WS_WSUM  = WS_WMAX + 1048576;   // 1 MB
constexpr size_t WS_PART  = WS_WSUM + 1048576;   // 128 f32

DEVI unsigned int f2bf(float f) {
  unsigned int u = __float_as_uint(f);
  return (u + 0x7fffu + ((u >> 16) & 1u)) >> 16;  // RNE f32->bf16 (finite)
}
DEVI float shflx(float v, int m) { return __shfl_xor(v, m, 64); }

// ---- prep: e -> B-fragment tile images (32-col tiles, scaled a*log2e) ----
// Tile t covers e-cols [32t, 32t+32). B-frag for k-step s, lane (hi,c):
//   byte = t*16384 + s*1024 + (hi*32 + c)*16 holds granule g = 2s+hi
//   (k in [8g, 8g+8)) of col c.   (R6/R11-validated layout, absmax 0)
__global__ void prep_e(const float* __restrict__ e, const float* __restrict__ lsp,
                       char* __restrict__ eimg, float* __restrict__ eterm) {
  const int et = blockIdx.x, t = threadIdx.x;
  const int c = t >> 3, o = t & 7;   // col in tile, octant of 256 k
  const int gc = et * 32 + c;
  const float a = __expf(-2.0f * lsp[0]);
  const float sab = a * LOG2E;       // fold score scale into the image
  const float* s = e + (size_t)gc * D + o * 32;
  float sq = 0.0f;
  unsigned int w[16];
#pragma unroll
  for (int i = 0; i < 8; ++i) {
    float4 x = *(const float4*)(s + i * 4);
    sq += x.x * x.x + x.y * x.y + x.z * x.z + x.w * x.w;
    w[2 * i]     = f2bf(sab * x.x) | (f2bf(sab * x.y) << 16);
    w[2 * i + 1] = f2bf(sab * x.z) | (f2bf(sab * x.w) << 16);
  }
  sq += shflx(sq, 1); sq += shflx(sq, 2); sq += shflx(sq, 4);  // 8-lane group
  char* base = eimg + (size_t)et * 16384;
#pragma unroll
  for (int i = 0; i < 4; ++i) {
    int g = o * 4 + i;  // 16B k-granule
    int phys = (g >> 1) * 1024 + (g & 1) * 512 + c * 16;
    uint4 pk; pk.x = w[4 * i]; pk.y = w[4 * i + 1];
    pk.z = w[4 * i + 2]; pk.w = w[4 * i + 3];
    *(uint4*)(base + phys) = pk;
  }
  if (o == 0) eterm[gc] = -0.5f * a * sq;   // natural-log units
}

// ---- main: 512 blocks x 1024 thr (16 waves, 1 block/CU, 4 waves/SIMD).
// Block = 128 z-rows in 2 chunks of 64 (dbuf LDS, bf16 XOR-swizzled).
// Wave = 64 rows x 32 e-cols: acc 2xf32x16 (32), A from LDS (2 reads/step),
// B from L2 eimg (1 load/step, 2-deep prefetch queue). Running (mx,sm) is
// 2 scalars/lane; cols owned by exactly one wave -> direct ws write. ----
__global__ __launch_bounds__(1024, 4)
void lse_main(const float* __restrict__ z, const char* __restrict__ eimg,
              const float* __restrict__ lsp, float* __restrict__ wmax,
              float* __restrict__ wsum) {
  extern __shared__ char smem[];      // zbuf[2][64 rows x 512B] = 65536
  __shared__ float ztm[2][64];        // z row terms (log2 units)

  const int tid = threadIdx.x;
  const int wid = tid >> 6, lane = tid & 63;
  const int l31 = lane & 31;   // z-row in row-group / C col is e-col
  const int hi  = lane >> 5;   // k-half of frags; C row-group bit
  const int bx = blockIdx.x;
  const float a = __expf(-2.0f * lsp[0]);
  const float ztf = -0.5f * a * LOG2E;

  // staging mapping: 16 thr/row, thread holds 2 granules (16 f32)
  const int srow = tid >> 4;          // 0..63
  const int gp   = (tid & 15) * 2;    // granule pair base (0,2,..,30)
  const float* zsrc = z + ((size_t)bx * 128 + srow) * D + gp * 8;

  float4 s0, s1, s2, s3;   // staging regs (granules gp, gp+1)
  auto ISSUE = [&](int chunk) {
    const float* p = zsrc + (size_t)chunk * 64 * D;
    s0 = *(const float4*)(p);      s1 = *(const float4*)(p + 4);
    s2 = *(const float4*)(p + 8);  s3 = *(const float4*)(p + 12);
  };
  auto COMMIT = [&](int buf) {
    float sq = s0.x * s0.x + s0.y * s0.y + s0.z * s0.z + s0.w * s0.w +
               s1.x * s1.x + s1.y * s1.y + s1.z * s1.z + s1.w * s1.w +
               s2.x * s2.x + s2.y * s2.y + s2.z * s2.z + s2.w * s2.w +
               s3.x * s3.x + s3.y * s3.y + s3.z * s3.z + s3.w * s3.w;
    sq += shflx(sq, 1); sq += shflx(sq, 2);
    sq += shflx(sq, 4); sq += shflx(sq, 8);    // 16 thr per row
    uint4 p0, p1;
    p0.x = f2bf(s0.x) | (f2bf(s0.y) << 16);
    p0.y = f2bf(s0.z) | (f2bf(s0.w) << 16);
    p0.z = f2bf(s1.x) | (f2bf(s1.y) << 16);
    p0.w = f2bf(s1.z) | (f2bf(s1.w) << 16);
    p1.x = f2bf(s2.x) | (f2bf(s2.y) << 16);
    p1.y = f2bf(s2.z) | (f2bf(s2.w) << 16);
    p1.z = f2bf(s3.x) | (f2bf(s3.y) << 16);
    p1.w = f2bf(s3.z) | (f2bf(s3.w) << 16);
    char* rb = smem + buf * 32768 + srow * 512;
    const int key = srow & 31;
    *(uint4*)(rb + ((gp ^ key) * 16))       = p0;
    *(uint4*)(rb + (((gp + 1) ^ key) * 16)) = p1;
    if ((tid & 15) == 0) ztm[buf][srow] = ztf * sq;
  };

  // B strip: wave wid owns e-cols [32*wid, 32*wid+32) = tile wid
  const char* bp = eimg + (size_t)wid * 16384 + lane * 16;

  ISSUE(0);
  COMMIT(0);
  __syncthreads();
  ISSUE(1);          // chunk-1 HBM latency hides under chunk-0 compute

  float rm = -1e30f, rs = 0.0f;   // running per-col LSE state (log2 domain)

#pragma unroll
  for (int c = 0; c < 2; ++c) {
    const char* ab0 = smem + c * 32768 + l31 * 512;          // rows 0..31
    const char* ab1 = smem + c * 32768 + (32 + l31) * 512;   // rows 32..63

    f32x16 acc0, acc1;
#pragma unroll
    for (int i = 0; i < 16; ++i) { acc0[i] = 0.f; acc1[i] = 0.f; }

    short8 Bq[2];   // 2-deep B prefetch queue (static idx after unroll)
    Bq[0] = *(const short8*)(bp);
    Bq[1] = *(const short8*)(bp + 1024);
#pragma unroll
    for (int s = 0; s < 16; ++s) {
      short8 Bc = Bq[s & 1];
      if (s + 2 < 16) Bq[s & 1] = *(const short8*)(bp + (s + 2) * 1024);
      const int slot = ((2 * s + hi) ^ l31) * 16;
      short8 A0 = *(const short8*)(ab0 + slot);
      short8 A1 = *(const short8*)(ab1 + slot);
      acc0 = __builtin_amdgcn_mfma_f32_32x32x16_bf16(A0, Bc, acc0, 0, 0, 0);
      acc1 = __builtin_amdgcn_mfma_f32_32x32x16_bf16(A1, Bc, acc1, 0, 0, 0);
    }

    // epilogue: lane = e-col (wid*32+l31); 32 z-rows in acc (+32 in partner).
    // C row = rg*32 + (r&3) + 8*(r>>2) + 4*hi -> zt as float4 at 8j+4hi.
    float4 zt0[4], zt1[4];
#pragma unroll
    for (int j = 0; j < 4; ++j) {
      zt0[j] = *(const float4*)&ztm[c][8 * j + 4 * hi];
      zt1[j] = *(const float4*)&ztm[c][32 + 8 * j + 4 * hi];
    }
    float v[32];
#pragma unroll
    for (int r = 0; r < 16; ++r) {
      v[r]      = acc0[r] + ((const float*)&zt0[r >> 2])[r & 3];
      v[16 + r] = acc1[r] + ((const float*)&zt1[r >> 2])[r & 3];
    }
    float mx = v[0];
#pragma unroll
    for (int i = 1; i < 32; ++i) mx = fmaxf(mx, v[i]);
    mx = fmaxf(mx, shflx(mx, 32));   // other 32 rows live in partner lane
    float sm = 0.0f;
#pragma unroll
    for (int i = 0; i < 32; ++i) sm += exp2f(v[i] - mx);
    sm += shflx(sm, 32);

    float nm = fmaxf(rm, mx);        // online merge (2 scalars of state)
    rs = rs * exp2f(rm - nm) + sm * exp2f(mx - nm);
    rm = nm;

    if (c == 0) {
      COMMIT(1);        // write chunk 1 into buf 1 (no race: other buffer)
      __syncthreads();  // commit visible before chunk-1 reads
    }
  }

  if (hi == 0) {   // both halves hold the merged result; lane<32 writes
    const int col = wid * 32 + l31;
    wmax[(size_t)bx * 512 + col] = rm;     // log2 domain
    wsum[(size_t)bx * 512 + col] = rs;
  }
}

// ---- merge the 4 row-blocks of each 512-row window, add eterm, reduce ----
__global__ void merge_b(const float* __restrict__ wmax, const float* __restrict__ wsum,
                        const float* __restrict__ eterm, float* __restrict__ partial) {
  __shared__ float sh[512];
  const int b = blockIdx.x, t = threadIdx.x;
  float m[4];
  float nm = -1e30f;
#pragma unroll
  for (int i = 0; i < 4; ++i) {
    m[i] = wmax[(size_t)(4 * b + i) * 512 + t];
    nm = fmaxf(nm, m[i]);
  }
  float s = 0.0f;
#pragma unroll
  for (int i = 0; i < 4; ++i)
    s += wsum[(size_t)(4 * b + i) * 512 + t] * exp2f(m[i] - nm);
  sh[t] = LN2 * (nm + log2f(s)) + eterm[t];   // back to natural units
  __syncthreads();
  for (int st = 256; st > 0; st >>= 1) {
    if (t < st) sh[t] += sh[t + st];
    __syncthreads();
  }
  if (t == 0) partial[b] = sh[0];
}

__global__ void final_k(const float* __restrict__ partial,
                        const float* __restrict__ lsp, float* __restrict__ out) {
  __shared__ float sh[128];
  const int t = threadIdx.x;
  sh[t] = partial[t];
  __syncthreads();
  for (int st = 64; st > 0; st >>= 1) {
    if (t < st) sh[t] += sh[t + st];
    __syncthreads();
  }
  if (t == 0) {
    float ls = lsp[0];
    out[0] = -sh[0] / 65536.0f + 128.0f * (2.0f * ls - 1.0f) + logf(512.0f);
  }
}

extern "C" void kernel_launch(void* const* d_in, const int* in_sizes, int n_in,
                              void* d_out, int out_size, void* d_ws, size_t ws_size,
                              hipStream_t stream) {
  const float* z   = (const float*)d_in[0];
  const float* e   = (const float*)d_in[1];
  const float* lsp = (const float*)d_in[2];
  float* out = (float*)d_out;
  char* ws = (char*)d_ws;
  char*  eimg    = ws + WS_EIMG;
  float* eterm   = (float*)(ws + WS_ETERM);
  float* wmax    = (float*)(ws + WS_WMAX);
  float* wsum    = (float*)(ws + WS_WSUM);
  float* partial = (float*)(ws + WS_PART);

  hipFuncSetAttribute(reinterpret_cast<const void*>(lse_main),
                      hipFuncAttributeMaxDynamicSharedMemorySize, 65536);
  prep_e<<<dim3(16), dim3(256), 0, stream>>>(e, lsp, eimg, eterm);
  lse_main<<<dim3(512), dim3(1024), 65536, stream>>>(z, eimg, lsp, wmax, wsum);
  merge_b<<<dim3(128), dim3(512), 0, stream>>>(wmax, wsum, eterm, partial);
  final_k<<<dim3(1), dim3(128), 0, stream>>>(partial, lsp, out);
}